// Round 4
// baseline (271.647 us; speedup 1.0000x reference)
//
#include <hip/hip_runtime.h>

// cost[b,dd,ii,j,c,uv] = (bounds? x[b,c,uv, ii+d*(4-u), j+d*(4-v)] : 0) * mask[b,uv,ii,j]
// d = dd-4, u=uv/9, v=uv%9.  out = cost (b,9,96,96,324) flat, then ctr = x[:,:,40,:,:].
//
// Block = (ii, dd, b, 16-wide j-chunk), 256 threads (4 waves), LDS ~24.4 KB ->
// 6 blocks/CU co-resident (6 independent barrier groups for latency hiding).
// LDS staged transposed with shift pre-applied; store phase = ds_read_b128 +
// contiguous aligned float4 nontemporal stores.

#define NAA 81
#define H 96
#define W 96
#define NC 4
#define ND 9
#define PLANE 9216          // 96*96
#define NR 324              // rows = c*81+uv
#define RS 340              // LDS column stride (floats): %4==0, %32==20 -> 4-way max
#define JB 16               // j per block
#define OUTROW 31104        // W*NR
#define CTR_OFF 53747712LL  // 2*9*96*96*324

typedef float f32x4 __attribute__((ext_vector_type(4)));

__global__ __launch_bounds__(256)
void build_cost_kernel(const float* __restrict__ x, const float* __restrict__ mask,
                       float* __restrict__ out) {
    __shared__ __align__(16) float xs[JB * RS];   // xs[jj*RS + row]  (21,760 B)
    __shared__ __align__(16) int   lut[2 * NR];   // per row: {xb_or_-1, (mb<<6)|(s+16)}

    const int ii  = blockIdx.x;          // spatial row i
    const int dd  = blockIdx.y;          // disparity index
    const int zz  = blockIdx.z;          // b*6 + j-chunk
    const int b   = zz / 6;
    const int jc  = zz - 6 * b;
    const int j0  = JB * jc;
    const int d   = dd - 4;
    const int tid = threadIdx.x;

    // ---- phase 0: packed per-row LUT (324 rows) ----
    for (int row = tid; row < NR; row += 256) {
        int c  = row / 81;
        int uv = row - 81 * c;
        int u  = uv / 9;
        int v  = uv - 9 * u;
        int ri = ii + d * (4 - u);
        int xb = ((b * NC + c) * NAA + uv) * PLANE + ri * W;
        int mb = ((b * NAA + uv) * H + ii) * W;
        int s  = d * (4 - v);
        lut[2 * row]     = ((unsigned)ri < (unsigned)H) ? xb : -1;
        lut[2 * row + 1] = (mb << 6) | (s + 16);
    }
    __syncthreads();

    // ---- phase 1: stage xs[jj][row] = x[row, ri, j+s] * mask[uv, ii, j] ----
    for (int idx = tid; idx < 81 * JB; idx += 256) {
        int rq = idx >> 4;               // row quad 0..80
        int jj = idx & (JB - 1);
        int j  = j0 + jj;
        int4 P0 = *(const int4*)&lut[8 * rq];       // rows 4rq, 4rq+1
        int4 P1 = *(const int4*)&lut[8 * rq + 4];   // rows 4rq+2, 4rq+3
        float4 v;
        {
            int xb = P0.x, B = P0.y;
            int s = (B & 63) - 16, col = j + s;
            float xv = x[max(xb, 0) + min(max(col, 0), W - 1)];
            float mv = mask[(B >> 6) + j];
            v.x = (xb >= 0 && (unsigned)col < (unsigned)W) ? xv * mv : 0.0f;
        }
        {
            int xb = P0.z, B = P0.w;
            int s = (B & 63) - 16, col = j + s;
            float xv = x[max(xb, 0) + min(max(col, 0), W - 1)];
            float mv = mask[(B >> 6) + j];
            v.y = (xb >= 0 && (unsigned)col < (unsigned)W) ? xv * mv : 0.0f;
        }
        {
            int xb = P1.x, B = P1.y;
            int s = (B & 63) - 16, col = j + s;
            float xv = x[max(xb, 0) + min(max(col, 0), W - 1)];
            float mv = mask[(B >> 6) + j];
            v.z = (xb >= 0 && (unsigned)col < (unsigned)W) ? xv * mv : 0.0f;
        }
        {
            int xb = P1.z, B = P1.w;
            int s = (B & 63) - 16, col = j + s;
            float xv = x[max(xb, 0) + min(max(col, 0), W - 1)];
            float mv = mask[(B >> 6) + j];
            v.w = (xb >= 0 && (unsigned)col < (unsigned)W) ? xv * mv : 0.0f;
        }
        *(float4*)&xs[jj * RS + 4 * rq] = v;
    }
    __syncthreads();

    // ---- phase 2: contiguous, aligned stores in output order ----
    // float index in xs for out-idx: j=idx/81, rq=idx-81j -> j*RS + 4*rq = 4*idx + 16*j
    const size_t obase = (size_t)((b * ND + dd) * H + ii) * OUTROW + (size_t)j0 * NR;
    for (int idx = tid; idx < 81 * JB; idx += 256) {
        int j = idx / 81;
        f32x4 v = *(const f32x4*)&xs[4 * idx + 16 * j];
        __builtin_nontemporal_store(v, (f32x4*)(out + obase + 4 * (size_t)idx));
    }

    // ---- ctr output: x[b,c,40,ii,:] (done by dd==4, jc==0 blocks) ----
    if (dd == 4 && jc == 0 && tid < 96) {
        int c = tid / 24;
        int q = tid - 24 * c;
        size_t so  = (size_t)((b * NC + c) * NAA + 40) * PLANE + (size_t)ii * W + 4 * q;
        size_t dst = CTR_OFF + (size_t)((b * NC + c) * H + ii) * W + 4 * q;
        f32x4 cv = *(const f32x4*)(x + so);
        __builtin_nontemporal_store(cv, (f32x4*)(out + dst));
    }
}

extern "C" void kernel_launch(void* const* d_in, const int* in_sizes, int n_in,
                              void* d_out, int out_size, void* d_ws, size_t ws_size,
                              hipStream_t stream) {
    const float* x    = (const float*)d_in[0];
    const float* mask = (const float*)d_in[1];
    float* out = (float*)d_out;
    dim3 grid(96, ND, 12);   // (ii, dd, b*6 + j-chunk)
    build_cost_kernel<<<grid, 256, 0, stream>>>(x, mask, out);
}